// Round 14
// baseline (1963.073 us; speedup 1.0000x reference)
//
#include <hip/hip_runtime.h>

#define N_ 8
#define S_ 2048
#define E_ 512
#define KL_ 2064          // S + P
#define NTT_ 65           // k-tiles of 32 (last covers 2048..2079; tail masked, V zero-padded)
#define VTSZ 1064960      // per-n VT2 elements: 65*512*32
#define SCALE2 0.063758723f   // (1/sqrt(512)) * log2(e)
#define NEGBIG -700.0f

typedef unsigned short u16;
typedef unsigned int u32;
typedef __attribute__((ext_vector_type(2))) float f32x2;
typedef __attribute__((ext_vector_type(4))) float f32x4;
typedef __attribute__((ext_vector_type(4))) short bf16x4;
typedef __attribute__((ext_vector_type(8))) short bf16x8;

__device__ __forceinline__ u16 f2bf(float x) {
  u32 u = __float_as_uint(x);
  u32 r = (u + 0x7FFFu + ((u >> 16) & 1u)) >> 16;
  return (u16)r;
}

__device__ __forceinline__ float exp2_fast(float x) {
  float r;
  asm("v_exp_f32 %0, %1" : "=v"(r) : "v"(x));
  return r;
}

__device__ __forceinline__ f32x4 mfma16(bf16x4 a, bf16x4 b, f32x4 c) {
#if __has_builtin(__builtin_amdgcn_mfma_f32_16x16x16bf16_1k)
  return __builtin_amdgcn_mfma_f32_16x16x16bf16_1k(a, b, c, 0, 0, 0);
#else
  f32x4 d;
  asm("v_mfma_f32_16x16x16_bf16 %0, %1, %2, %3" : "=v"(d) : "v"(a), "v"(b), "v"(c));
  return d;
#endif
}

__device__ __forceinline__ void gload_lds16(const void* g, void* l) {
  __builtin_amdgcn_global_load_lds((const __attribute__((address_space(1))) unsigned int*)g,
                                   (__attribute__((address_space(3))) unsigned int*)l, 16, 0, 0);
}

// ---------------- mask pack: 1 bit per (q,l), layout bm[n][lword=64][q=2048] ----------------
__global__ __launch_bounds__(256) void maskpack_kernel(const int* __restrict__ mask,
                                                       u32* __restrict__ bm) {
  const int t = threadIdx.x;
  const int w = t >> 6, lane = t & 63;
  const int blk = blockIdx.x;
  const int n = blk >> 9;
  const int qrow = ((blk & 511) << 2) + w;
  const int* row = mask + ((size_t)n * S_ + qrow) * S_;
  __shared__ u32 tl[4][64];
  u32 myword = 0;
  #pragma unroll 4
  for (int k = 0; k < 32; ++k) {
    int v = row[k * 64 + lane];
    unsigned long long b = __ballot(v != 0);
    if ((lane >> 1) == k) myword = (lane & 1) ? (u32)(b >> 32) : (u32)b;
  }
  tl[w][lane] = myword;
  __syncthreads();
  const int qq = t & 3, wi = t >> 2;
  const int qb = ((blk & 511) << 2) + qq;
  bm[((size_t)n * 64 + wi) * S_ + qb] = tl[qq][wi];
}

// ---------------- projections (MFMA): Qp/Kp bf16 natural, V l-tiled VT2[n][lt][e][32] ----------------
__global__ __launch_bounds__(256, 2) void proj_kernel(
    const float* __restrict__ V_, const float* __restrict__ K_, const float* __restrict__ Q_,
    const float* __restrict__ Wv, const float* __restrict__ Wk, const float* __restrict__ Wq,
    u16* __restrict__ Kp, u16* __restrict__ Qp, u16* __restrict__ VT) {
  __shared__ u16 xt[64 * 512];
  __shared__ u16 wt[64 * 64];
  const int tz = blockIdx.y;
  const float* X = (tz == 0) ? V_ : (tz == 1) ? K_ : Q_;
  const float* W = (tz == 0) ? Wv : (tz == 1) ? Wk : Wq;
  const int t = threadIdx.x, lane = t & 63, w = t >> 6, g = lane >> 4, li = lane & 15;
  const int rb = blockIdx.x * 64;
  const int nn = rb >> 11, sb = rb & 2047;

  for (int c = t; c < 512; c += 256) {
    int r = c >> 3, s = c & 7;
    float4 a = *(const float4*)&W[r * 64 + s * 8];
    float4 b = *(const float4*)&W[r * 64 + s * 8 + 4];
    bf16x8 v = {(short)f2bf(a.x), (short)f2bf(a.y), (short)f2bf(a.z), (short)f2bf(a.w),
                (short)f2bf(b.x), (short)f2bf(b.y), (short)f2bf(b.z), (short)f2bf(b.w)};
    *(bf16x8*)&wt[r * 64 + ((s ^ (r & 7)) * 8)] = v;
  }
  for (int c = t; c < 4096; c += 256) {
    int r = c >> 6, s = c & 63;
    const float* src = &X[(size_t)(rb + r) * 512 + s * 8];
    float4 a = *(const float4*)src;
    float4 b = *(const float4*)(src + 4);
    bf16x8 v = {(short)f2bf(a.x), (short)f2bf(a.y), (short)f2bf(a.z), (short)f2bf(a.w),
                (short)f2bf(b.x), (short)f2bf(b.y), (short)f2bf(b.z), (short)f2bf(b.w)};
    *(bf16x8*)&xt[r * 512 + ((s ^ (r & 7)) * 8)] = v;
  }
  __syncthreads();

  bf16x8 fx[8][2];
  #pragma unroll
  for (int h = 0; h < 8; ++h)
    #pragma unroll
    for (int dh = 0; dh < 2; ++dh) {
      int row = w * 16 + li;
      fx[h][dh] = *(const bf16x8*)&xt[row * 512 + (((h * 8 + dh * 4 + g) ^ (row & 7)) * 8)];
    }
  bf16x8 fw[4][2];
  #pragma unroll
  for (int c = 0; c < 4; ++c)
    #pragma unroll
    for (int dh = 0; dh < 2; ++dh) {
      int row = c * 16 + li;
      fw[c][dh] = *(const bf16x8*)&wt[row * 64 + (((dh * 4 + g) ^ (row & 7)) * 8)];
    }

  f32x4 C[8][4];
  #pragma unroll
  for (int h = 0; h < 8; ++h)
    #pragma unroll
    for (int c = 0; c < 4; ++c) C[h][c] = (f32x4){0.f, 0.f, 0.f, 0.f};

  if (tz == 0) {
    #pragma unroll
    for (int h = 0; h < 8; ++h)
      #pragma unroll
      for (int dh = 0; dh < 2; ++dh)
        #pragma unroll
        for (int c = 0; c < 4; ++c)
          C[h][c] = __builtin_amdgcn_mfma_f32_16x16x32_bf16(fw[c][dh], fx[h][dh], C[h][c], 0, 0, 0);
    #pragma unroll
    for (int h = 0; h < 8; ++h)
      #pragma unroll
      for (int c = 0; c < 4; ++c)
        #pragma unroll
        for (int r = 0; r < 4; ++r) {
          int e = h * 64 + c * 16 + g * 4 + r;
          int l = sb + w * 16 + li;
          VT[(((size_t)nn * 65 + (l >> 5)) * 512 + e) * 32 + (l & 31)] = f2bf(C[h][c][r]);
        }
  } else {
    #pragma unroll
    for (int h = 0; h < 8; ++h)
      #pragma unroll
      for (int dh = 0; dh < 2; ++dh)
        #pragma unroll
        for (int c = 0; c < 4; ++c)
          C[h][c] = __builtin_amdgcn_mfma_f32_16x16x32_bf16(fx[h][dh], fw[c][dh], C[h][c], 0, 0, 0);
    #pragma unroll
    for (int h = 0; h < 8; ++h)
      #pragma unroll
      for (int c = 0; c < 4; ++c)
        #pragma unroll
        for (int r = 0; r < 4; ++r) {
          int e = h * 64 + c * 16 + li;
          u16 val = f2bf(C[h][c][r]);
          if (tz == 2) Qp[(size_t)(rb + w * 16 + g * 4 + r) * 512 + e] = val;
          else Kp[((size_t)nn * KL_ + sb + w * 16 + g * 4 + r) * 512 + e] = val;
        }
  }
}

// ---------------- persistent tokens (K rows 2048..2063; V tile 64 zero-padded) ----------------
__global__ __launch_bounds__(256) void persist_kernel(const float* __restrict__ pk,
                                                      const float* __restrict__ pv,
                                                      u16* __restrict__ Kp, u16* __restrict__ VT) {
  int id = blockIdx.x * 256 + threadIdx.x;
  if (id < 65536) {
    int n = id >> 13, p = (id >> 9) & 15, e = id & 511;
    Kp[((size_t)n * KL_ + S_ + p) * 512 + e] = f2bf(pk[p * 512 + e]);
  } else {
    int rem = id - 65536;
    int n = rem >> 14, p = (rem >> 9) & 31, e = rem & 511;
    u16 val = (p < 16) ? f2bf(pv[p * 512 + e]) : (u16)0;
    VT[(((size_t)n * 65 + 64) * 512 + e) * 32 + p] = val;
  }
}

// ---------------- Z pass: key-halved, single-buffer strict-sync ----------------
__global__ __launch_bounds__(512, 4) void z_kernel(
    const u16* __restrict__ Qp, const u16* __restrict__ Kp,
    const u32* __restrict__ bm, const float* __restrict__ pre_th,
    float* __restrict__ Zp) {
  __shared__ __align__(16) u16 KtB[32 * 512];      // 32 KB single buffer
  __shared__ u32 mlds[33 * 64];                    // 8.4 KB
  __shared__ float Zbuf[2 * 64 * 8];               // 4 KB

  const int t = threadIdx.x, lane = t & 63, w = t >> 6, g = lane >> 4, li = lane & 15;
  const int qw = w & 3, lh = w >> 2;
  const int bid = blockIdx.x;
  const int n = bid & 7;                 // batch pinned to XCD
  const int rem = bid >> 3;              // 0..63
  const int qb = rem >> 1, kh = rem & 1;
  const int q0 = qb * 64;
  const int tb = kh ? 33 : 0;
  const int nt = kh ? 32 : 33;
  const int wc = kh ? 31 : 33;           // valid mask words (tiles < 64)
  const int myq = q0 + qw * 16 + li;
  const float myq_f = (float)myq;

  const u16* Kbase = Kp + (size_t)n * KL_ * 512;

  #define ZSTAGE_K(tile) {                                                              \
    _Pragma("unroll")                                                                   \
    for (int i_ = 0; i_ < 4; ++i_) {                                                    \
      int row_ = w + i_ * 8;                                                            \
      gload_lds16(Kbase + (size_t)((tile) * 32 + row_) * 512 + ((lane ^ (row_ & 7)) * 8),\
                  &KtB[row_ * 512]);                                                    \
    } }

  for (int idx = t; idx < wc * 64; idx += 512)
    mlds[idx] = bm[((size_t)n * 64 + tb + (idx >> 6)) * S_ + q0 + (idx & 63)];

  bf16x8 qf[8][2];
  {
    const u16* qrow = Qp + (size_t)(n * S_ + myq) * 512;
    #pragma unroll
    for (int h = 0; h < 8; ++h)
      #pragma unroll
      for (int dh = 0; dh < 2; ++dh)
        qf[h][dh] = *(const bf16x8*)(qrow + h * 64 + dh * 32 + g * 8);
  }
  float nms[8];
  #pragma unroll
  for (int i = 0; i < 8; ++i) {
    float a = 0.f;
    #pragma unroll
    for (int j = 0; j < 8; ++j) a += pre_th[i * 8 + j] * exp2f(-(float)(j + 1));
    nms[i] = -a * SCALE2;
  }

  float Zr[8];
  #pragma unroll
  for (int i = 0; i < 8; ++i) Zr[i] = 0.f;

  __syncthreads();   // mlds visible

  for (int j = 0; j < nt; ++j) {
    const int tile = tb + j;
    ZSTAGE_K(tile)
    __builtin_amdgcn_sched_barrier(0);
    asm volatile("s_waitcnt vmcnt(0)" ::: "memory");
    __builtin_amdgcn_s_barrier();                 // all stages landed
    const u16* kb = &KtB[0];
    f32x4 C[8];
    #pragma unroll
    for (int h = 0; h < 8; ++h) C[h] = (f32x4){0.f, 0.f, 0.f, 0.f};
    #pragma unroll
    for (int h = 0; h < 8; ++h)
      #pragma unroll
      for (int dh = 0; dh < 2; ++dh) {
        bf16x8 a = *(const bf16x8*)(kb + (lh * 16 + li) * 512 + (((h * 8 + dh * 4 + g) ^ (li & 7)) * 8));
        C[h] = __builtin_amdgcn_mfma_f32_16x16x32_bf16(a, qf[h][dh], C[h], 0, 0, 0);
      }
    u32 mbits;
    float dist[4];
    const int l0 = tile * 32 + lh * 16 + g * 4;
    if (tile < 64) {
      mbits = (mlds[j * 64 + qw * 16 + li] >> (lh * 16 + g * 4)) & 0xFu;
      #pragma unroll
      for (int r = 0; r < 4; ++r) dist[r] = fabsf(myq_f - (float)(l0 + r));
    } else {
      mbits = (lh == 0) ? 0xFu : 0u;
      #pragma unroll
      for (int r = 0; r < 4; ++r) dist[r] = 0.f;
    }
    const bool al = (tile < 64);
    #pragma unroll
    for (int i = 0; i < 8; ++i) {
      f32x2 al2 = (f32x2){0.f, 0.f}, ah2 = (f32x2){0.f, 0.f};
      #pragma unroll
      for (int j2 = 0; j2 < 8; ++j2) {
        float p = pre_th[i * 8 + j2];
        al2 += p * (f32x2){C[j2].x, C[j2].y};
        ah2 += p * (f32x2){C[j2].z, C[j2].w};
      }
      float t0 = fmaf(al2.x, SCALE2, -64.f);
      float t1 = fmaf(al2.y, SCALE2, -64.f);
      float t2 = fmaf(ah2.x, SCALE2, -64.f);
      float t3 = fmaf(ah2.y, SCALE2, -64.f);
      if (al) {
        t0 = fmaf(dist[0], nms[i], t0); t1 = fmaf(dist[1], nms[i], t1);
        t2 = fmaf(dist[2], nms[i], t2); t3 = fmaf(dist[3], nms[i], t3);
      }
      t0 = (mbits & 1u) ? t0 : NEGBIG; t1 = (mbits & 2u) ? t1 : NEGBIG;
      t2 = (mbits & 4u) ? t2 : NEGBIG; t3 = (mbits & 8u) ? t3 : NEGBIG;
      Zr[i] += (exp2_fast(t0) + exp2_fast(t1)) + (exp2_fast(t2) + exp2_fast(t3));
    }
    __builtin_amdgcn_s_barrier();                 // all reads done before next overwrite
  }
  __syncthreads();

  #pragma unroll
  for (int i = 0; i < 8; ++i) {
    Zr[i] += __shfl_xor(Zr[i], 16);
    Zr[i] += __shfl_xor(Zr[i], 32);
  }
  if (lane < 16) {
    #pragma unroll
    for (int i = 0; i < 8; ++i) Zbuf[(lh * 64 + qw * 16 + li) * 8 + i] = Zr[i];
  }
  __syncthreads();
  {
    int q = t >> 3, i = t & 7;
    float val = Zbuf[q * 8 + i] + Zbuf[(64 + q) * 8 + i];
    Zp[((size_t)(kh * 8 + n) * 2048 + q0 + q) * 8 + i] = val;
  }
  #undef ZSTAGE_K
}

// ---------------- PV pass: single-buffer strict-sync, 80 KB LDS -> 2 blocks/CU ----------------
__global__ __launch_bounds__(512, 4) void pv_kernel(
    const u16* __restrict__ Qp, const u16* __restrict__ Kp, const u16* __restrict__ VT,
    const u32* __restrict__ bm, const float* __restrict__ pre_th,
    const float* __restrict__ post_th, const float* __restrict__ Zp,
    u16* __restrict__ Ohb) {
  __shared__ __align__(16) char smem[81920];           // 80 KB -> 2 blocks/CU
  u16* KtB = (u16*)smem;                               // [32][512]  (32 KB)
  u16* VtB = (u16*)(smem + 32768);                     // tile[512][32] (32 KB)
  u32* mlds = (u32*)(smem + 65536);                    // [64][64]   (16 KB)

  const int t = threadIdx.x, lane = t & 63, w = t >> 6, g = lane >> 4, li = lane & 15;
  const int qw = w & 3, lh = w >> 2;
  const int bid = blockIdx.x;
  const int n = bid & 7;
  const int q0 = (bid >> 3) * 64;
  const int myq = q0 + qw * 16 + li;
  const float myq_f = (float)myq;

  const u16* Kbase = Kp + (size_t)n * KL_ * 512;
  const u16* Vbase = VT + (size_t)n * VTSZ;

  #define STAGE_K(tile) {                                                               \
    _Pragma("unroll")                                                                   \
    for (int i_ = 0; i_ < 4; ++i_) {                                                    \
      int row_ = w + i_ * 8;                                                            \
      gload_lds16(Kbase + (size_t)((tile) * 32 + row_) * 512 + ((lane ^ (row_ & 7)) * 8),\
                  KtB + row_ * 512);                                                    \
    } }
  #define STAGE_V(tile) {                                                               \
    _Pragma("unroll")                                                                   \
    for (int i_ = 0; i_ < 4; ++i_) {                                                    \
      int c_ = t + i_ * 512;                                                            \
      int e_ = c_ >> 2, q16_ = c_ & 3;                                                  \
      gload_lds16(Vbase + (size_t)(tile) * 16384 + e_ * 32 + ((q16_ ^ (e_ & 3)) * 8),   \
                  VtB + (i_ * 512 + w * 64) * 8);                                       \
    } }

  for (int idx = t; idx < 4096; idx += 512)
    mlds[idx] = bm[((size_t)n * 64 + (idx >> 6)) * S_ + q0 + (idx & 63)];

  bf16x8 qf[8][2];
  {
    const u16* qrow = Qp + (size_t)(n * S_ + myq) * 512;
    #pragma unroll
    for (int h = 0; h < 8; ++h)
      #pragma unroll
      for (int dh = 0; dh < 2; ++dh)
        qf[h][dh] = *(const bf16x8*)(qrow + h * 64 + dh * 32 + g * 8);
  }
  float nms[8];
  #pragma unroll
  for (int i = 0; i < 8; ++i) {
    float a = 0.f;
    #pragma unroll
    for (int j = 0; j < 8; ++j) a += pre_th[i * 8 + j] * exp2f(-(float)(j + 1));
    nms[i] = -a * SCALE2;
  }
  float nm1[8];
  {
    const float* zp0 = Zp + ((size_t)n * 2048 + myq) * 8;
    const float* zp1 = Zp + ((size_t)(8 + n) * 2048 + myq) * 8;
    #pragma unroll
    for (int i = 0; i < 8; ++i) nm1[i] = -(64.f + __log2f(zp0[i] + zp1[i]));
  }

  f32x4 O[8][4];
  #pragma unroll
  for (int o = 0; o < 8; ++o)
    #pragma unroll
    for (int dc = 0; dc < 4; ++dc) O[o][dc] = (f32x4){0.f, 0.f, 0.f, 0.f};

  const int cloff = (((lh * 2 + (g >> 1)) ^ (li & 3)) * 8) + (g & 1) * 4;  // u16 units

  __syncthreads();   // mlds visible

  for (int tt = 0; tt < NTT_; ++tt) {
    STAGE_K(tt) STAGE_V(tt)
    __builtin_amdgcn_sched_barrier(0);
    asm volatile("s_waitcnt vmcnt(0)" ::: "memory");
    __builtin_amdgcn_s_barrier();                 // all stages landed
    const u16* kb = KtB;
    const u16* vb = VtB;
    f32x4 C[8];
    #pragma unroll
    for (int h = 0; h < 8; ++h) C[h] = (f32x4){0.f, 0.f, 0.f, 0.f};
    #pragma unroll
    for (int h = 0; h < 8; ++h)
      #pragma unroll
      for (int dh = 0; dh < 2; ++dh) {
        bf16x8 a = *(const bf16x8*)(kb + (lh * 16 + li) * 512 + (((h * 8 + dh * 4 + g) ^ (li & 7)) * 8));
        C[h] = __builtin_amdgcn_mfma_f32_16x16x32_bf16(a, qf[h][dh], C[h], 0, 0, 0);
      }
    u32 mbits;
    float dist[4];
    const int l0 = tt * 32 + lh * 16 + g * 4;
    if (tt < 64) {
      mbits = (mlds[tt * 64 + qw * 16 + li] >> (lh * 16 + g * 4)) & 0xFu;
      #pragma unroll
      for (int r = 0; r < 4; ++r) dist[r] = fabsf(myq_f - (float)(l0 + r));
    } else {
      mbits = (lh == 0) ? 0xFu : 0u;
      #pragma unroll
      for (int r = 0; r < 4; ++r) dist[r] = 0.f;
    }
    f32x2 accl[8], acch[8];
    #pragma unroll
    for (int i = 0; i < 8; ++i) { accl[i] = (f32x2){0.f, 0.f}; acch[i] = (f32x2){0.f, 0.f}; }
    #pragma unroll
    for (int j = 0; j < 8; ++j) {
      f32x2 elo = {C[j].x, C[j].y}, ehi = {C[j].z, C[j].w};
      #pragma unroll
      for (int i = 0; i < 8; ++i) {
        float p = pre_th[i * 8 + j];
        accl[i] += p * elo; acch[i] += p * ehi;
      }
    }
    const bool al = (tt < 64);
    f32x2 ppl[8], pph[8];
    #pragma unroll
    for (int i = 0; i < 8; ++i) {
      float t0 = fmaf(accl[i].x, SCALE2, nm1[i]);
      float t1 = fmaf(accl[i].y, SCALE2, nm1[i]);
      float t2 = fmaf(acch[i].x, SCALE2, nm1[i]);
      float t3 = fmaf(acch[i].y, SCALE2, nm1[i]);
      if (al) {
        t0 = fmaf(dist[0], nms[i], t0); t1 = fmaf(dist[1], nms[i], t1);
        t2 = fmaf(dist[2], nms[i], t2); t3 = fmaf(dist[3], nms[i], t3);
      }
      t0 = (mbits & 1u) ? t0 : NEGBIG; t1 = (mbits & 2u) ? t1 : NEGBIG;
      t2 = (mbits & 4u) ? t2 : NEGBIG; t3 = (mbits & 8u) ? t3 : NEGBIG;
      ppl[i] = (f32x2){exp2_fast(t0), exp2_fast(t1)};
      pph[i] = (f32x2){exp2_fast(t2), exp2_fast(t3)};
    }
    f32x2 pol[8], poh[8];
    #pragma unroll
    for (int o = 0; o < 8; ++o) { pol[o] = (f32x2){0.f, 0.f}; poh[o] = (f32x2){0.f, 0.f}; }
    #pragma unroll
    for (int i = 0; i < 8; ++i) {
      #pragma unroll
      for (int o = 0; o < 8; ++o) {
        float c = post_th[o * 8 + i];
        pol[o] += c * ppl[i]; poh[o] += c * pph[i];
      }
    }
    #pragma unroll
    for (int o = 0; o < 8; ++o) {
      bf16x4 pa = {(short)f2bf(pol[o].x), (short)f2bf(pol[o].y),
                   (short)f2bf(poh[o].x), (short)f2bf(poh[o].y)};
      #pragma unroll
      for (int dc = 0; dc < 4; ++dc) {
        int e = o * 64 + dc * 16 + li;
        bf16x4 b = *(const bf16x4*)(vb + e * 32 + cloff);
        O[o][dc] = mfma16(pa, b, O[o][dc]);
      }
    }
    __builtin_amdgcn_s_barrier();                 // all reads done before next overwrite
  }
  __syncthreads();   // all compute done before ep overlay

  // ---- epilogue: combine l-halves via 64 KB LDS overlay, in 2 phases (q-strips 0-1, 2-3) ----
  float* ep = (float*)smem;   // 64 KB overlay on KtB+VtB
  #pragma unroll
  for (int ph = 0; ph < 2; ++ph) {
    if (lh == 1 && (qw >> 1) == ph) {
      #pragma unroll
      for (int o = 0; o < 8; ++o)
        #pragma unroll
        for (int dc = 0; dc < 4; ++dc)
          *(f32x4*)&ep[(qw & 1) * 8192 + ((o * 4 + dc) * 64 + li * 4 + g) * 4] = O[o][dc];
    }
    __syncthreads();
    if (lh == 0 && (qw >> 1) == ph) {
      u16* dst = Ohb + (size_t)(n * S_ + q0 + qw * 16) * 512;
      #pragma unroll
      for (int o = 0; o < 8; ++o)
        #pragma unroll
        for (int dc = 0; dc < 4; ++dc) {
          f32x4 oth = *(const f32x4*)&ep[(qw & 1) * 8192 + ((o * 4 + dc) * 64 + li * 4 + g) * 4];
          f32x4 v = O[o][dc] + oth;
          int e = o * 64 + dc * 16 + li;
          #pragma unroll
          for (int r = 0; r < 4; ++r) dst[(size_t)(g * 4 + r) * 512 + e] = f2bf(v[r]);
        }
    }
    __syncthreads();
  }
  #undef STAGE_K
  #undef STAGE_V
}

// ---------------- output projection (bf16 MFMA): out = Ohb @ Wo^T + bo ----------------
__global__ __launch_bounds__(256) void out_proj_kernel(
    const u16* __restrict__ Ohb, const float* __restrict__ Wo,
    const float* __restrict__ bo, float* __restrict__ out) {
  __shared__ __align__(16) u16 As[2][128 * 32];
  __shared__ __align__(16) u16 Bs[2][128 * 32];
  const int t = threadIdx.x, lane = t & 63, w = t >> 6, g = lane >> 4, li = lane & 15;
  const int wq = w & 1, wp = w >> 1;
  const int r0 = blockIdx.y * 128, c0 = blockIdx.x * 128;

  #define STAGE_A(buf, ks) {                                                  \
    _Pragma("unroll")                                                         \
    for (int i_ = 0; i_ < 2; ++i_) {                                          \
      int c_ = t + i_ * 256;                                                  \
      gload_lds16(Ohb + (size_t)(r0 + (c_ >> 2)) * 512 + (ks) + (c_ & 3) * 8, \
                  &As[buf][(i_ * 256 + w * 64) * 8]);                         \
    } }
  #define STAGE_B(buf, ks) {                                                  \
    _Pragma("unroll")                                                         \
    for (int i_ = 0; i_ < 2; ++i_) {                                          \
      int c_ = t + i_ * 256;                                                  \
      const float* s_ = &Wo[(size_t)(c0 + (c_ >> 2)) * 512 + (ks) + (c_ & 3) * 8]; \
      float4 a_ = *(const float4*)s_;                                         \
      float4 b_ = *(const float4*)(s_ + 4);                                   \
      bf16x8 v_ = {(short)f2bf(a_.x), (short)f2bf(a_.y), (short)f2bf(a_.z), (short)f2bf(a_.w), \
                   (short)f2bf(b_.x), (short)f2bf(b_.y), (short)f2bf(b_.z), (short)f2bf(b_.w)}; \
      *(bf16x8*)&Bs[buf][c_ * 8] = v_;                                        \
    } }

  f32x4 acc[4][4];
  #pragma unroll
  for (int m = 0; m < 4; ++m)
    #pragma unroll
    for (int nn = 0; nn < 4; ++nn) acc[m][nn] = (f32x4){0.f, 0.f, 0.f, 0.f};

  STAGE_A(0, 0)
  STAGE_B(0, 0)
  __syncthreads();
  for (int s = 0; s < 16; ++s) {
    if (s + 1 < 16) { STAGE_A((s + 1) & 1, (s + 1) * 32) STAGE_B((s + 1) & 1, (s + 1) * 32) }
    const u16* ab = As[s & 1];
    const u16* bb = Bs[s & 1];
    bf16x8 af[4], bf[4];
    #pragma unroll
    for (int m = 0; m < 4; ++m) af[m] = *(const bf16x8*)(ab + (wp * 64 + m * 16 + li) * 32 + g * 8);
    #pragma unroll
    for (int nn = 0; nn < 4; ++nn) bf[nn] = *(const bf16x8*)(bb + (wq * 64 + nn * 16 + li) * 32 + g * 8);
    #pragma unroll
    for (int m = 0; m < 4; ++m)
      #pragma unroll
      for (int nn = 0; nn < 4; ++nn)
        acc[m][nn] = __builtin_amdgcn_mfma_f32_16x16x32_bf16(af[m], bf[nn], acc[m][nn], 0, 0, 0);
    __syncthreads();
  }
  #pragma unroll
  for (int nn = 0; nn < 4; ++nn) {
    int col = c0 + wq * 64 + nn * 16 + li;
    float bv = bo[col];
    #pragma unroll
    for (int m = 0; m < 4; ++m)
      #pragma unroll
      for (int r = 0; r < 4; ++r)
        out[(size_t)(r0 + wp * 64 + m * 16 + g * 4 + r) * 512 + col] = acc[m][nn][r] + bv;
  }
  #undef STAGE_A
  #undef STAGE_B
}

extern "C" void kernel_launch(void* const* d_in, const int* in_sizes, int n_in,
                              void* d_out, int out_size, void* d_ws, size_t ws_size,
                              hipStream_t stream) {
  const float* values  = (const float*)d_in[0];
  const float* keys    = (const float*)d_in[1];
  const float* queries = (const float*)d_in[2];
  const int*   mask    = (const int*)d_in[3];
  const float* Wv      = (const float*)d_in[4];
  const float* Wk      = (const float*)d_in[5];
  const float* Wq      = (const float*)d_in[6];
  const float* Wo      = (const float*)d_in[7];
  const float* bo      = (const float*)d_in[8];
  const float* pre_th  = (const float*)d_in[9];
  const float* post_th = (const float*)d_in[10];
  const float* pk      = (const float*)d_in[11];
  const float* pv      = (const float*)d_in[12];

  char* ws = (char*)d_ws;
  u16*  Qp  = (u16*)ws;                          // 16,777,216
  u16*  Kp  = (u16*)(ws + 16777216);             // 16,908,288
  u16*  VT  = (u16*)(ws + 33685504);             // 8*65*512*32*2 = 17,039,360
  u16*  Ohb = (u16*)(ws + 50724864);             // 16,777,216
  u32*  bm  = (u32*)(ws + 67502080);             // 4,194,304
  float* Zp = (float*)(ws + 71696384);           // 2*8*2048*8*4 = 1,048,576 (end 72,744,960)

  hipLaunchKernelGGL(maskpack_kernel, dim3(4096), dim3(256), 0, stream, mask, bm);
  hipLaunchKernelGGL(proj_kernel, dim3(256, 3), dim3(256), 0, stream,
                     values, keys, queries, Wv, Wk, Wq, Kp, Qp, VT);
  hipLaunchKernelGGL(persist_kernel, dim3(768), dim3(256), 0, stream, pk, pv, Kp, VT);
  hipLaunchKernelGGL(z_kernel, dim3(512), dim3(512), 0, stream,
                     Qp, Kp, bm, pre_th, Zp);
  hipLaunchKernelGGL(pv_kernel, dim3(256), dim3(512), 0, stream,
                     Qp, Kp, VT, bm, pre_th, post_th, Zp, Ohb);
  hipLaunchKernelGGL(out_proj_kernel, dim3(4, 128), dim3(256), 0, stream,
                     Ohb, Wo, bo, (float*)d_out);
}

// Round 15
// 838.777 us; speedup vs baseline: 2.3404x; 2.3404x over previous
//
#include <hip/hip_runtime.h>

#define N_ 8
#define S_ 2048
#define E_ 512
#define KL_ 2064          // S + P
#define NTT_ 65           // k-tiles of 32 (last covers 2048..2079; tail masked, V zero-padded)
#define VTSZ 1064960      // per-n VT2 elements: 65*512*32
#define SCALE2 0.063758723f   // (1/sqrt(512)) * log2(e)
#define NEGBIG -700.0f

typedef unsigned short u16;
typedef unsigned int u32;
typedef __attribute__((ext_vector_type(2))) float f32x2;
typedef __attribute__((ext_vector_type(4))) float f32x4;
typedef __attribute__((ext_vector_type(4))) short bf16x4;
typedef __attribute__((ext_vector_type(8))) short bf16x8;

__device__ __forceinline__ u16 f2bf(float x) {
  u32 u = __float_as_uint(x);
  u32 r = (u + 0x7FFFu + ((u >> 16) & 1u)) >> 16;
  return (u16)r;
}

__device__ __forceinline__ float exp2_fast(float x) {
  float r;
  asm("v_exp_f32 %0, %1" : "=v"(r) : "v"(x));
  return r;
}

__device__ __forceinline__ f32x4 mfma16(bf16x4 a, bf16x4 b, f32x4 c) {
#if __has_builtin(__builtin_amdgcn_mfma_f32_16x16x16bf16_1k)
  return __builtin_amdgcn_mfma_f32_16x16x16bf16_1k(a, b, c, 0, 0, 0);
#else
  f32x4 d;
  asm("v_mfma_f32_16x16x16_bf16 %0, %1, %2, %3" : "=v"(d) : "v"(a), "v"(b), "v"(c));
  return d;
#endif
}

__device__ __forceinline__ void gload_lds16(const void* g, void* l) {
  __builtin_amdgcn_global_load_lds((const __attribute__((address_space(1))) unsigned int*)g,
                                   (__attribute__((address_space(3))) unsigned int*)l, 16, 0, 0);
}

// ---------------- mask pack: 1 bit per (q,l), layout bm[n][lword=64][q=2048] ----------------
__global__ __launch_bounds__(256) void maskpack_kernel(const int* __restrict__ mask,
                                                       u32* __restrict__ bm) {
  const int t = threadIdx.x;
  const int w = t >> 6, lane = t & 63;
  const int blk = blockIdx.x;
  const int n = blk >> 9;
  const int qrow = ((blk & 511) << 2) + w;
  const int* row = mask + ((size_t)n * S_ + qrow) * S_;
  __shared__ u32 tl[4][64];
  u32 myword = 0;
  #pragma unroll 4
  for (int k = 0; k < 32; ++k) {
    int v = row[k * 64 + lane];
    unsigned long long b = __ballot(v != 0);
    if ((lane >> 1) == k) myword = (lane & 1) ? (u32)(b >> 32) : (u32)b;
  }
  tl[w][lane] = myword;
  __syncthreads();
  const int qq = t & 3, wi = t >> 2;
  const int qb = ((blk & 511) << 2) + qq;
  bm[((size_t)n * 64 + wi) * S_ + qb] = tl[qq][wi];
}

// ---------------- projections (MFMA): Qp/Kp bf16 natural, V l-tiled VT2[n][lt][e][32] ----------------
__global__ __launch_bounds__(256, 2) void proj_kernel(
    const float* __restrict__ V_, const float* __restrict__ K_, const float* __restrict__ Q_,
    const float* __restrict__ Wv, const float* __restrict__ Wk, const float* __restrict__ Wq,
    u16* __restrict__ Kp, u16* __restrict__ Qp, u16* __restrict__ VT) {
  __shared__ u16 xt[64 * 512];
  __shared__ u16 wt[64 * 64];
  const int tz = blockIdx.y;
  const float* X = (tz == 0) ? V_ : (tz == 1) ? K_ : Q_;
  const float* W = (tz == 0) ? Wv : (tz == 1) ? Wk : Wq;
  const int t = threadIdx.x, lane = t & 63, w = t >> 6, g = lane >> 4, li = lane & 15;
  const int rb = blockIdx.x * 64;
  const int nn = rb >> 11, sb = rb & 2047;

  for (int c = t; c < 512; c += 256) {
    int r = c >> 3, s = c & 7;
    float4 a = *(const float4*)&W[r * 64 + s * 8];
    float4 b = *(const float4*)&W[r * 64 + s * 8 + 4];
    bf16x8 v = {(short)f2bf(a.x), (short)f2bf(a.y), (short)f2bf(a.z), (short)f2bf(a.w),
                (short)f2bf(b.x), (short)f2bf(b.y), (short)f2bf(b.z), (short)f2bf(b.w)};
    *(bf16x8*)&wt[r * 64 + ((s ^ (r & 7)) * 8)] = v;
  }
  for (int c = t; c < 4096; c += 256) {
    int r = c >> 6, s = c & 63;
    const float* src = &X[(size_t)(rb + r) * 512 + s * 8];
    float4 a = *(const float4*)src;
    float4 b = *(const float4*)(src + 4);
    bf16x8 v = {(short)f2bf(a.x), (short)f2bf(a.y), (short)f2bf(a.z), (short)f2bf(a.w),
                (short)f2bf(b.x), (short)f2bf(b.y), (short)f2bf(b.z), (short)f2bf(b.w)};
    *(bf16x8*)&xt[r * 512 + ((s ^ (r & 7)) * 8)] = v;
  }
  __syncthreads();

  bf16x8 fx[8][2];
  #pragma unroll
  for (int h = 0; h < 8; ++h)
    #pragma unroll
    for (int dh = 0; dh < 2; ++dh) {
      int row = w * 16 + li;
      fx[h][dh] = *(const bf16x8*)&xt[row * 512 + (((h * 8 + dh * 4 + g) ^ (row & 7)) * 8)];
    }
  bf16x8 fw[4][2];
  #pragma unroll
  for (int c = 0; c < 4; ++c)
    #pragma unroll
    for (int dh = 0; dh < 2; ++dh) {
      int row = c * 16 + li;
      fw[c][dh] = *(const bf16x8*)&wt[row * 64 + (((dh * 4 + g) ^ (row & 7)) * 8)];
    }

  f32x4 C[8][4];
  #pragma unroll
  for (int h = 0; h < 8; ++h)
    #pragma unroll
    for (int c = 0; c < 4; ++c) C[h][c] = (f32x4){0.f, 0.f, 0.f, 0.f};

  if (tz == 0) {
    #pragma unroll
    for (int h = 0; h < 8; ++h)
      #pragma unroll
      for (int dh = 0; dh < 2; ++dh)
        #pragma unroll
        for (int c = 0; c < 4; ++c)
          C[h][c] = __builtin_amdgcn_mfma_f32_16x16x32_bf16(fw[c][dh], fx[h][dh], C[h][c], 0, 0, 0);
    #pragma unroll
    for (int h = 0; h < 8; ++h)
      #pragma unroll
      for (int c = 0; c < 4; ++c)
        #pragma unroll
        for (int r = 0; r < 4; ++r) {
          int e = h * 64 + c * 16 + g * 4 + r;
          int l = sb + w * 16 + li;
          VT[(((size_t)nn * 65 + (l >> 5)) * 512 + e) * 32 + (l & 31)] = f2bf(C[h][c][r]);
        }
  } else {
    #pragma unroll
    for (int h = 0; h < 8; ++h)
      #pragma unroll
      for (int dh = 0; dh < 2; ++dh)
        #pragma unroll
        for (int c = 0; c < 4; ++c)
          C[h][c] = __builtin_amdgcn_mfma_f32_16x16x32_bf16(fx[h][dh], fw[c][dh], C[h][c], 0, 0, 0);
    #pragma unroll
    for (int h = 0; h < 8; ++h)
      #pragma unroll
      for (int c = 0; c < 4; ++c)
        #pragma unroll
        for (int r = 0; r < 4; ++r) {
          int e = h * 64 + c * 16 + li;
          u16 val = f2bf(C[h][c][r]);
          if (tz == 2) Qp[(size_t)(rb + w * 16 + g * 4 + r) * 512 + e] = val;
          else Kp[((size_t)nn * KL_ + sb + w * 16 + g * 4 + r) * 512 + e] = val;
        }
  }
}

// ---------------- persistent tokens (K rows 2048..2063; V tile 64 zero-padded) ----------------
__global__ __launch_bounds__(256) void persist_kernel(const float* __restrict__ pk,
                                                      const float* __restrict__ pv,
                                                      u16* __restrict__ Kp, u16* __restrict__ VT) {
  int id = blockIdx.x * 256 + threadIdx.x;
  if (id < 65536) {
    int n = id >> 13, p = (id >> 9) & 15, e = id & 511;
    Kp[((size_t)n * KL_ + S_ + p) * 512 + e] = f2bf(pk[p * 512 + e]);
  } else {
    int rem = id - 65536;
    int n = rem >> 14, p = (rem >> 9) & 31, e = rem & 511;
    u16 val = (p < 16) ? f2bf(pv[p * 512 + e]) : (u16)0;
    VT[(((size_t)n * 65 + 64) * 512 + e) * 32 + p] = val;
  }
}

// ---------------- Z pass: key-halved, single-buffer strict-sync ----------------
__global__ __launch_bounds__(512, 2) void z_kernel(
    const u16* __restrict__ Qp, const u16* __restrict__ Kp,
    const u32* __restrict__ bm, const float* __restrict__ pre_th,
    float* __restrict__ Zp) {
  __shared__ __align__(16) u16 KtB[32 * 512];      // 32 KB single buffer
  __shared__ u32 mlds[33 * 64];                    // 8.4 KB
  __shared__ float Zbuf[2 * 64 * 8];               // 4 KB

  const int t = threadIdx.x, lane = t & 63, w = t >> 6, g = lane >> 4, li = lane & 15;
  const int qw = w & 3, lh = w >> 2;
  const int bid = blockIdx.x;
  const int n = bid & 7;                 // batch pinned to XCD
  const int rem = bid >> 3;              // 0..63
  const int qb = rem >> 1, kh = rem & 1;
  const int q0 = qb * 64;
  const int tb = kh ? 33 : 0;
  const int nt = kh ? 32 : 33;
  const int wc = kh ? 31 : 33;           // valid mask words (tiles < 64)
  const int myq = q0 + qw * 16 + li;
  const float myq_f = (float)myq;

  const u16* Kbase = Kp + (size_t)n * KL_ * 512;

  #define ZSTAGE_K(tile) {                                                              \
    _Pragma("unroll")                                                                   \
    for (int i_ = 0; i_ < 4; ++i_) {                                                    \
      int row_ = w + i_ * 8;                                                            \
      gload_lds16(Kbase + (size_t)((tile) * 32 + row_) * 512 + ((lane ^ (row_ & 7)) * 8),\
                  &KtB[row_ * 512]);                                                    \
    } }

  for (int idx = t; idx < wc * 64; idx += 512)
    mlds[idx] = bm[((size_t)n * 64 + tb + (idx >> 6)) * S_ + q0 + (idx & 63)];

  bf16x8 qf[8][2];
  {
    const u16* qrow = Qp + (size_t)(n * S_ + myq) * 512;
    #pragma unroll
    for (int h = 0; h < 8; ++h)
      #pragma unroll
      for (int dh = 0; dh < 2; ++dh)
        qf[h][dh] = *(const bf16x8*)(qrow + h * 64 + dh * 32 + g * 8);
  }
  float nms[8];
  #pragma unroll
  for (int i = 0; i < 8; ++i) {
    float a = 0.f;
    #pragma unroll
    for (int j = 0; j < 8; ++j) a += pre_th[i * 8 + j] * exp2f(-(float)(j + 1));
    nms[i] = -a * SCALE2;
  }

  float Zr[8];
  #pragma unroll
  for (int i = 0; i < 8; ++i) Zr[i] = 0.f;

  __syncthreads();   // mlds visible

  for (int j = 0; j < nt; ++j) {
    const int tile = tb + j;
    ZSTAGE_K(tile)
    __builtin_amdgcn_sched_barrier(0);
    asm volatile("s_waitcnt vmcnt(0)" ::: "memory");
    __builtin_amdgcn_s_barrier();                 // all stages landed
    const u16* kb = &KtB[0];
    f32x4 C[8];
    #pragma unroll
    for (int h = 0; h < 8; ++h) C[h] = (f32x4){0.f, 0.f, 0.f, 0.f};
    #pragma unroll
    for (int h = 0; h < 8; ++h)
      #pragma unroll
      for (int dh = 0; dh < 2; ++dh) {
        bf16x8 a = *(const bf16x8*)(kb + (lh * 16 + li) * 512 + (((h * 8 + dh * 4 + g) ^ (li & 7)) * 8));
        C[h] = __builtin_amdgcn_mfma_f32_16x16x32_bf16(a, qf[h][dh], C[h], 0, 0, 0);
      }
    u32 mbits;
    float dist[4];
    const int l0 = tile * 32 + lh * 16 + g * 4;
    if (tile < 64) {
      mbits = (mlds[j * 64 + qw * 16 + li] >> (lh * 16 + g * 4)) & 0xFu;
      #pragma unroll
      for (int r = 0; r < 4; ++r) dist[r] = fabsf(myq_f - (float)(l0 + r));
    } else {
      mbits = (lh == 0) ? 0xFu : 0u;
      #pragma unroll
      for (int r = 0; r < 4; ++r) dist[r] = 0.f;
    }
    const bool al = (tile < 64);
    #pragma unroll
    for (int i = 0; i < 8; ++i) {
      f32x2 al2 = (f32x2){0.f, 0.f}, ah2 = (f32x2){0.f, 0.f};
      #pragma unroll
      for (int j2 = 0; j2 < 8; ++j2) {
        float p = pre_th[i * 8 + j2];
        al2 += p * (f32x2){C[j2].x, C[j2].y};
        ah2 += p * (f32x2){C[j2].z, C[j2].w};
      }
      float t0 = fmaf(al2.x, SCALE2, -64.f);
      float t1 = fmaf(al2.y, SCALE2, -64.f);
      float t2 = fmaf(ah2.x, SCALE2, -64.f);
      float t3 = fmaf(ah2.y, SCALE2, -64.f);
      if (al) {
        t0 = fmaf(dist[0], nms[i], t0); t1 = fmaf(dist[1], nms[i], t1);
        t2 = fmaf(dist[2], nms[i], t2); t3 = fmaf(dist[3], nms[i], t3);
      }
      t0 = (mbits & 1u) ? t0 : NEGBIG; t1 = (mbits & 2u) ? t1 : NEGBIG;
      t2 = (mbits & 4u) ? t2 : NEGBIG; t3 = (mbits & 8u) ? t3 : NEGBIG;
      Zr[i] += (exp2_fast(t0) + exp2_fast(t1)) + (exp2_fast(t2) + exp2_fast(t3));
    }
    __builtin_amdgcn_s_barrier();                 // all reads done before next overwrite
  }
  __syncthreads();

  #pragma unroll
  for (int i = 0; i < 8; ++i) {
    Zr[i] += __shfl_xor(Zr[i], 16);
    Zr[i] += __shfl_xor(Zr[i], 32);
  }
  if (lane < 16) {
    #pragma unroll
    for (int i = 0; i < 8; ++i) Zbuf[(lh * 64 + qw * 16 + li) * 8 + i] = Zr[i];
  }
  __syncthreads();
  {
    int q = t >> 3, i = t & 7;
    float val = Zbuf[q * 8 + i] + Zbuf[(64 + q) * 8 + i];
    Zp[((size_t)(kh * 8 + n) * 2048 + q0 + q) * 8 + i] = val;
  }
  #undef ZSTAGE_K
}

// ---------------- PV pass: single-buffer strict-sync, 80 KB LDS (2 blocks/CU via LDS), natural VGPR ----------------
__global__ __launch_bounds__(512, 2) void pv_kernel(
    const u16* __restrict__ Qp, const u16* __restrict__ Kp, const u16* __restrict__ VT,
    const u32* __restrict__ bm, const float* __restrict__ pre_th,
    const float* __restrict__ post_th, const float* __restrict__ Zp,
    u16* __restrict__ Ohb) {
  __shared__ __align__(16) char smem[81920];           // 80 KB -> 2 blocks/CU (LDS-limited)
  u16* KtB = (u16*)smem;                               // [32][512]  (32 KB)
  u16* VtB = (u16*)(smem + 32768);                     // tile[512][32] (32 KB)
  u32* mlds = (u32*)(smem + 65536);                    // [64][64]   (16 KB)

  const int t = threadIdx.x, lane = t & 63, w = t >> 6, g = lane >> 4, li = lane & 15;
  const int qw = w & 3, lh = w >> 2;
  const int bid = blockIdx.x;
  const int n = bid & 7;
  const int q0 = (bid >> 3) * 64;
  const int myq = q0 + qw * 16 + li;
  const float myq_f = (float)myq;

  const u16* Kbase = Kp + (size_t)n * KL_ * 512;
  const u16* Vbase = VT + (size_t)n * VTSZ;

  #define STAGE_K(tile) {                                                               \
    _Pragma("unroll")                                                                   \
    for (int i_ = 0; i_ < 4; ++i_) {                                                    \
      int row_ = w + i_ * 8;                                                            \
      gload_lds16(Kbase + (size_t)((tile) * 32 + row_) * 512 + ((lane ^ (row_ & 7)) * 8),\
                  KtB + row_ * 512);                                                    \
    } }
  #define STAGE_V(tile) {                                                               \
    _Pragma("unroll")                                                                   \
    for (int i_ = 0; i_ < 4; ++i_) {                                                    \
      int c_ = t + i_ * 512;                                                            \
      int e_ = c_ >> 2, q16_ = c_ & 3;                                                  \
      gload_lds16(Vbase + (size_t)(tile) * 16384 + e_ * 32 + ((q16_ ^ (e_ & 3)) * 8),   \
                  VtB + (i_ * 512 + w * 64) * 8);                                       \
    } }

  for (int idx = t; idx < 4096; idx += 512)
    mlds[idx] = bm[((size_t)n * 64 + (idx >> 6)) * S_ + q0 + (idx & 63)];

  bf16x8 qf[8][2];
  {
    const u16* qrow = Qp + (size_t)(n * S_ + myq) * 512;
    #pragma unroll
    for (int h = 0; h < 8; ++h)
      #pragma unroll
      for (int dh = 0; dh < 2; ++dh)
        qf[h][dh] = *(const bf16x8*)(qrow + h * 64 + dh * 32 + g * 8);
  }
  float nms[8];
  #pragma unroll
  for (int i = 0; i < 8; ++i) {
    float a = 0.f;
    #pragma unroll
    for (int j = 0; j < 8; ++j) a += pre_th[i * 8 + j] * exp2f(-(float)(j + 1));
    nms[i] = -a * SCALE2;
  }
  float nm1[8];
  {
    const float* zp0 = Zp + ((size_t)n * 2048 + myq) * 8;
    const float* zp1 = Zp + ((size_t)(8 + n) * 2048 + myq) * 8;
    #pragma unroll
    for (int i = 0; i < 8; ++i) nm1[i] = -(64.f + __log2f(zp0[i] + zp1[i]));
  }

  f32x4 O[8][4];
  #pragma unroll
  for (int o = 0; o < 8; ++o)
    #pragma unroll
    for (int dc = 0; dc < 4; ++dc) O[o][dc] = (f32x4){0.f, 0.f, 0.f, 0.f};

  const int cloff = (((lh * 2 + (g >> 1)) ^ (li & 3)) * 8) + (g & 1) * 4;  // u16 units

  __syncthreads();   // mlds visible

  for (int tt = 0; tt < NTT_; ++tt) {
    STAGE_K(tt) STAGE_V(tt)
    __builtin_amdgcn_sched_barrier(0);
    asm volatile("s_waitcnt vmcnt(0)" ::: "memory");
    __builtin_amdgcn_s_barrier();                 // all stages landed
    const u16* kb = KtB;
    const u16* vb = VtB;
    f32x4 C[8];
    #pragma unroll
    for (int h = 0; h < 8; ++h) C[h] = (f32x4){0.f, 0.f, 0.f, 0.f};
    #pragma unroll
    for (int h = 0; h < 8; ++h)
      #pragma unroll
      for (int dh = 0; dh < 2; ++dh) {
        bf16x8 a = *(const bf16x8*)(kb + (lh * 16 + li) * 512 + (((h * 8 + dh * 4 + g) ^ (li & 7)) * 8));
        C[h] = __builtin_amdgcn_mfma_f32_16x16x32_bf16(a, qf[h][dh], C[h], 0, 0, 0);
      }
    u32 mbits;
    float dist[4];
    const int l0 = tt * 32 + lh * 16 + g * 4;
    if (tt < 64) {
      mbits = (mlds[tt * 64 + qw * 16 + li] >> (lh * 16 + g * 4)) & 0xFu;
      #pragma unroll
      for (int r = 0; r < 4; ++r) dist[r] = fabsf(myq_f - (float)(l0 + r));
    } else {
      mbits = (lh == 0) ? 0xFu : 0u;
      #pragma unroll
      for (int r = 0; r < 4; ++r) dist[r] = 0.f;
    }
    f32x2 accl[8], acch[8];
    #pragma unroll
    for (int i = 0; i < 8; ++i) { accl[i] = (f32x2){0.f, 0.f}; acch[i] = (f32x2){0.f, 0.f}; }
    #pragma unroll
    for (int j = 0; j < 8; ++j) {
      f32x2 elo = {C[j].x, C[j].y}, ehi = {C[j].z, C[j].w};
      #pragma unroll
      for (int i = 0; i < 8; ++i) {
        float p = pre_th[i * 8 + j];
        accl[i] += p * elo; acch[i] += p * ehi;
      }
    }
    const bool al = (tt < 64);
    f32x2 ppl[8], pph[8];
    #pragma unroll
    for (int i = 0; i < 8; ++i) {
      float t0 = fmaf(accl[i].x, SCALE2, nm1[i]);
      float t1 = fmaf(accl[i].y, SCALE2, nm1[i]);
      float t2 = fmaf(acch[i].x, SCALE2, nm1[i]);
      float t3 = fmaf(acch[i].y, SCALE2, nm1[i]);
      if (al) {
        t0 = fmaf(dist[0], nms[i], t0); t1 = fmaf(dist[1], nms[i], t1);
        t2 = fmaf(dist[2], nms[i], t2); t3 = fmaf(dist[3], nms[i], t3);
      }
      t0 = (mbits & 1u) ? t0 : NEGBIG; t1 = (mbits & 2u) ? t1 : NEGBIG;
      t2 = (mbits & 4u) ? t2 : NEGBIG; t3 = (mbits & 8u) ? t3 : NEGBIG;
      ppl[i] = (f32x2){exp2_fast(t0), exp2_fast(t1)};
      pph[i] = (f32x2){exp2_fast(t2), exp2_fast(t3)};
    }
    f32x2 pol[8], poh[8];
    #pragma unroll
    for (int o = 0; o < 8; ++o) { pol[o] = (f32x2){0.f, 0.f}; poh[o] = (f32x2){0.f, 0.f}; }
    #pragma unroll
    for (int i = 0; i < 8; ++i) {
      #pragma unroll
      for (int o = 0; o < 8; ++o) {
        float c = post_th[o * 8 + i];
        pol[o] += c * ppl[i]; poh[o] += c * pph[i];
      }
    }
    #pragma unroll
    for (int o = 0; o < 8; ++o) {
      bf16x4 pa = {(short)f2bf(pol[o].x), (short)f2bf(pol[o].y),
                   (short)f2bf(poh[o].x), (short)f2bf(poh[o].y)};
      #pragma unroll
      for (int dc = 0; dc < 4; ++dc) {
        int e = o * 64 + dc * 16 + li;
        bf16x4 b = *(const bf16x4*)(vb + e * 32 + cloff);
        O[o][dc] = mfma16(pa, b, O[o][dc]);
      }
    }
    __builtin_amdgcn_s_barrier();                 // all reads done before next overwrite
  }
  __syncthreads();   // all compute done before ep overlay

  // ---- epilogue: combine l-halves via 64 KB LDS overlay, in 2 phases (q-strips 0-1, 2-3) ----
  float* ep = (float*)smem;   // 64 KB overlay on KtB+VtB
  #pragma unroll
  for (int ph = 0; ph < 2; ++ph) {
    if (lh == 1 && (qw >> 1) == ph) {
      #pragma unroll
      for (int o = 0; o < 8; ++o)
        #pragma unroll
        for (int dc = 0; dc < 4; ++dc)
          *(f32x4*)&ep[(qw & 1) * 8192 + ((o * 4 + dc) * 64 + li * 4 + g) * 4] = O[o][dc];
    }
    __syncthreads();
    if (lh == 0 && (qw >> 1) == ph) {
      u16* dst = Ohb + (size_t)(n * S_ + q0 + qw * 16) * 512;
      #pragma unroll
      for (int o = 0; o < 8; ++o)
        #pragma unroll
        for (int dc = 0; dc < 4; ++dc) {
          f32x4 oth = *(const f32x4*)&ep[(qw & 1) * 8192 + ((o * 4 + dc) * 64 + li * 4 + g) * 4];
          f32x4 v = O[o][dc] + oth;
          int e = o * 64 + dc * 16 + li;
          #pragma unroll
          for (int r = 0; r < 4; ++r) dst[(size_t)(g * 4 + r) * 512 + e] = f2bf(v[r]);
        }
    }
    __syncthreads();
  }
  #undef STAGE_K
  #undef STAGE_V
}

// ---------------- output projection (bf16 MFMA): out = Ohb @ Wo^T + bo ----------------
__global__ __launch_bounds__(256) void out_proj_kernel(
    const u16* __restrict__ Ohb, const float* __restrict__ Wo,
    const float* __restrict__ bo, float* __restrict__ out) {
  __shared__ __align__(16) u16 As[2][128 * 32];
  __shared__ __align__(16) u16 Bs[2][128 * 32];
  const int t = threadIdx.x, lane = t & 63, w = t >> 6, g = lane >> 4, li = lane & 15;
  const int wq = w & 1, wp = w >> 1;
  const int r0 = blockIdx.y * 128, c0 = blockIdx.x * 128;

  #define STAGE_A(buf, ks) {                                                  \
    _Pragma("unroll")                                                         \
    for (int i_ = 0; i_ < 2; ++i_) {                                          \
      int c_ = t + i_ * 256;                                                  \
      gload_lds16(Ohb + (size_t)(r0 + (c_ >> 2)) * 512 + (ks) + (c_ & 3) * 8, \
                  &As[buf][(i_ * 256 + w * 64) * 8]);                         \
    } }
  #define STAGE_B(buf, ks) {                                                  \
    _Pragma("unroll")                                                         \
    for (int i_ = 0; i_ < 2; ++i_) {                                          \
      int c_ = t + i_ * 256;                                                  \
      const float* s_ = &Wo[(size_t)(c0 + (c_ >> 2)) * 512 + (ks) + (c_ & 3) * 8]; \
      float4 a_ = *(const float4*)s_;                                         \
      float4 b_ = *(const float4*)(s_ + 4);                                   \
      bf16x8 v_ = {(short)f2bf(a_.x), (short)f2bf(a_.y), (short)f2bf(a_.z), (short)f2bf(a_.w), \
                   (short)f2bf(b_.x), (short)f2bf(b_.y), (short)f2bf(b_.z), (short)f2bf(b_.w)}; \
      *(bf16x8*)&Bs[buf][c_ * 8] = v_;                                        \
    } }

  f32x4 acc[4][4];
  #pragma unroll
  for (int m = 0; m < 4; ++m)
    #pragma unroll
    for (int nn = 0; nn < 4; ++nn) acc[m][nn] = (f32x4){0.f, 0.f, 0.f, 0.f};

  STAGE_A(0, 0)
  STAGE_B(0, 0)
  __syncthreads();
  for (int s = 0; s < 16; ++s) {
    if (s + 1 < 16) { STAGE_A((s + 1) & 1, (s + 1) * 32) STAGE_B((s + 1) & 1, (s + 1) * 32) }
    const u16* ab = As[s & 1];
    const u16* bb = Bs[s & 1];
    bf16x8 af[4], bf[4];
    #pragma unroll
    for (int m = 0; m < 4; ++m) af[m] = *(const bf16x8*)(ab + (wp * 64 + m * 16 + li) * 32 + g * 8);
    #pragma unroll
    for (int nn = 0; nn < 4; ++nn) bf[nn] = *(const bf16x8*)(bb + (wq * 64 + nn * 16 + li) * 32 + g * 8);
    #pragma unroll
    for (int m = 0; m < 4; ++m)
      #pragma unroll
      for (int nn = 0; nn < 4; ++nn)
        acc[m][nn] = __builtin_amdgcn_mfma_f32_16x16x32_bf16(af[m], bf[nn], acc[m][nn], 0, 0, 0);
    __syncthreads();
  }
  #pragma unroll
  for (int nn = 0; nn < 4; ++nn) {
    int col = c0 + wq * 64 + nn * 16 + li;
    float bv = bo[col];
    #pragma unroll
    for (int m = 0; m < 4; ++m)
      #pragma unroll
      for (int r = 0; r < 4; ++r)
        out[(size_t)(r0 + wp * 64 + m * 16 + g * 4 + r) * 512 + col] = acc[m][nn][r] + bv;
  }
  #undef STAGE_A
  #undef STAGE_B
}

extern "C" void kernel_launch(void* const* d_in, const int* in_sizes, int n_in,
                              void* d_out, int out_size, void* d_ws, size_t ws_size,
                              hipStream_t stream) {
  const float* values  = (const float*)d_in[0];
  const float* keys    = (const float*)d_in[1];
  const float* queries = (const float*)d_in[2];
  const int*   mask    = (const int*)d_in[3];
  const float* Wv      = (const float*)d_in[4];
  const float* Wk      = (const float*)d_in[5];
  const float* Wq      = (const float*)d_in[6];
  const float* Wo      = (const float*)d_in[7];
  const float* bo      = (const float*)d_in[8];
  const float* pre_th  = (const float*)d_in[9];
  const float* post_th = (const float*)d_in[10];
  const float* pk      = (const float*)d_in[11];
  const float* pv      = (const float*)d_in[12];

  char* ws = (char*)d_ws;
  u16*  Qp  = (u16*)ws;                          // 16,777,216
  u16*  Kp  = (u16*)(ws + 16777216);             // 16,908,288
  u16*  VT  = (u16*)(ws + 33685504);             // 8*65*512*32*2 = 17,039,360
  u16*  Ohb = (u16*)(ws + 50724864);             // 16,777,216
  u32*  bm  = (u32*)(ws + 67502080);             // 4,194,304
  float* Zp = (float*)(ws + 71696384);           // 2*8*2048*8*4 = 1,048,576 (end 72,744,960)

  hipLaunchKernelGGL(maskpack_kernel, dim3(4096), dim3(256), 0, stream, mask, bm);
  hipLaunchKernelGGL(proj_kernel, dim3(256, 3), dim3(256), 0, stream,
                     values, keys, queries, Wv, Wk, Wq, Kp, Qp, VT);
  hipLaunchKernelGGL(persist_kernel, dim3(768), dim3(256), 0, stream, pk, pv, Kp, VT);
  hipLaunchKernelGGL(z_kernel, dim3(512), dim3(512), 0, stream,
                     Qp, Kp, bm, pre_th, Zp);
  hipLaunchKernelGGL(pv_kernel, dim3(256), dim3(512), 0, stream,
                     Qp, Kp, VT, bm, pre_th, post_th, Zp, Ohb);
  hipLaunchKernelGGL(out_proj_kernel, dim3(4, 128), dim3(256), 0, stream,
                     Ohb, Wo, bo, (float*)d_out);
}